// Round 9
// baseline (488.224 us; speedup 1.0000x reference)
//
#include <hip/hip_runtime.h>

typedef __attribute__((ext_vector_type(4))) float f32x4;
typedef __bf16 bf16x8 __attribute__((ext_vector_type(8)));
typedef unsigned int u32x4 __attribute__((ext_vector_type(4)));
typedef unsigned short ushort_t;

#define T_TOK 8192   // B*S
#define DIM   1024   // D
#define NRCOL 2048   // N_FEAT * R

#define LGKM0() asm volatile("s_waitcnt lgkmcnt(0)" ::: "memory")
#define VMW(n)  asm volatile("s_waitcnt vmcnt(" #n ")" ::: "memory")
#define SB0()   __builtin_amdgcn_sched_barrier(0)
#define BAR()   __builtin_amdgcn_s_barrier()

static __device__ __forceinline__ unsigned short f2bf(float f) {
  unsigned int u = __builtin_bit_cast(unsigned int, f);
  u += 0x7fffu + ((u >> 16) & 1u);          // RNE
  return (unsigned short)(u >> 16);
}
static __device__ __forceinline__ float bflo(unsigned u) {
  return __builtin_bit_cast(float, u << 16);
}
static __device__ __forceinline__ float bfhi(unsigned u) {
  return __builtin_bit_cast(float, u & 0xffff0000u);
}
static __device__ __forceinline__ void gload16(const void* g, void* l) {
  __builtin_amdgcn_global_load_lds((const __attribute__((address_space(1))) void*)g,
                                   (__attribute__((address_space(3))) void*)l, 16, 0, 0);
}

// ---------------- f32 -> bf16 straight cast (x) ----------------
__global__ __launch_bounds__(256) void cvt_f32_bf16(const float* __restrict__ in,
                                                    unsigned short* __restrict__ out,
                                                    int n4) {
  int i = blockIdx.x * 256 + threadIdx.x;
  const int stride = gridDim.x * 256;
  const float4* in4 = (const float4*)in;
  uint2* o4 = (uint2*)out;
  for (; i < n4; i += stride) {
    float4 v = in4[i];
    uint2 o;
    o.x = (unsigned)f2bf(v.x) | ((unsigned)f2bf(v.y) << 16);
    o.y = (unsigned)f2bf(v.z) | ((unsigned)f2bf(v.w) << 16);
    o4[i] = o;
  }
}

// ---------------- tiled transpose + cast ----------------
__global__ __launch_bounds__(256) void tcvt(const float* __restrict__ src,
                                            unsigned short* __restrict__ dst,
                                            int rows, int cols,
                                            long sstride, long dstride) {
  src += (size_t)blockIdx.z * sstride;
  dst += (size_t)blockIdx.z * dstride;
  __shared__ float tile[32][33];
  const int tx = threadIdx.x & 31, ty = threadIdx.x >> 5;
  const int r0 = blockIdx.y * 32, c0 = blockIdx.x * 32;
  #pragma unroll
  for (int i = 0; i < 32; i += 8)
    tile[ty + i][tx] = src[(size_t)(r0 + ty + i) * cols + c0 + tx];
  __syncthreads();
  #pragma unroll
  for (int i = 0; i < 32; i += 8)
    dst[(size_t)(c0 + ty + i) * rows + r0 + tx] = f2bf(tile[tx][ty + i]);
}

// =====================================================================
// gemmP: unchanged R8 pipelined GEMM (used for gemm1, 256x256 BK=32).
// =====================================================================
template<int BM, int BK, int K, bool OUT_BF16>
__global__ __launch_bounds__(512, 2) void gemmP(const ushort_t* __restrict__ A,
                                                const ushort_t* __restrict__ Bt,
                                                void* __restrict__ Cp, int N) {
  constexpr int nt = K / BK;
  constexpr int KS = BK / 32;
  constexpr int MF = BM / 32;
  constexpr int CH = BK / 8;
  constexpr int AR = BM * BK * 2 / 8192;
  constexpr int BR = 256 * BK * 2 / 8192;
  constexpr int LPT = AR + BR;
  __shared__ ushort_t As[3][BM * BK];
  __shared__ ushort_t Bs[3][256 * BK];

  const int tid = threadIdx.x;
  const int nx = gridDim.x;
  const int orig = blockIdx.y * nx + blockIdx.x;
  const int q = (nx * gridDim.y) >> 3;
  const int swz = (orig & 7) * q + (orig >> 3);
  const int bx = swz % nx, by = swz / nx;

  const int lane = tid & 63, wv = tid >> 6;
  const int wm = wv >> 2, wn = wv & 3;
  const int lrow = lane & 15, lk = lane >> 4;

  const ushort_t* Ab = A + (size_t)by * BM * K;
  const ushort_t* Bb = Bt + (size_t)bx * 256 * K;

  const int srow = tid * 16 / (BK * 2);
  const int sch = ((tid * 16 >> 4) & (CH - 1)) ^ (srow & (CH - 1));
  constexpr int RPR = 8192 / (BK * 2);
  const ushort_t* pA[AR];
  const ushort_t* pB[BR];
  #pragma unroll
  for (int r = 0; r < AR; ++r) pA[r] = Ab + (size_t)(r * RPR + srow) * K + sch * 8;
  #pragma unroll
  for (int r = 0; r < BR; ++r) pB[r] = Bb + (size_t)(r * RPR + srow) * K + sch * 8;
  const int dL = tid * 8;

  int oA[MF], oB[4];
  #pragma unroll
  for (int m = 0; m < MF; ++m) {
    const int r = wm * (BM / 2) + m * 16 + lrow;
    oA[m] = r * BK + (lk ^ (r & (CH - 1))) * 8;
  }
  #pragma unroll
  for (int n = 0; n < 4; ++n) {
    const int r = wn * 64 + n * 16 + lrow;
    oB[n] = r * BK + (lk ^ (r & (CH - 1))) * 8;
  }

  f32x4 acc[MF][4];
  #pragma unroll
  for (int m = 0; m < MF; ++m)
    #pragma unroll
    for (int n = 0; n < 4; ++n)
      acc[m][n] = (f32x4){0.f, 0.f, 0.f, 0.f};

  auto stage = [&](int s, int adv) {
    #pragma unroll
    for (int r = 0; r < AR; ++r) gload16(pA[r] + adv, (void*)&As[s][r * 4096 + dL]);
    #pragma unroll
    for (int r = 0; r < BR; ++r) gload16(pB[r] + adv, (void*)&Bs[s][r * 4096 + dL]);
  };

  stage(0, 0);
  stage(1, BK);
  if constexpr (LPT == 4) VMW(4); else VMW(6);
  SB0(); BAR(); SB0();

  bf16x8 av[2][MF][KS], bv01[2][KS], bv23[2][KS];
  #pragma unroll
  for (int m = 0; m < MF; ++m)
    #pragma unroll
    for (int ks = 0; ks < KS; ++ks)
      av[0][m][ks] = *(const bf16x8*)&As[0][oA[m] ^ (ks * 32)];
  #pragma unroll
  for (int n = 0; n < 2; ++n)
    #pragma unroll
    for (int ks = 0; ks < KS; ++ks)
      bv01[n][ks] = *(const bf16x8*)&Bs[0][oB[n] ^ (ks * 32)];

  #pragma unroll
  for (int t = 0; t < nt; ++t) {
    const int s = t % 3, s1 = (t + 1) % 3, s2 = (t + 2) % 3;
    const int p = t & 1;
    if (t + 2 < nt) stage(s2, (t + 2) * BK);
    #pragma unroll
    for (int n = 0; n < 2; ++n)
      #pragma unroll
      for (int ks = 0; ks < KS; ++ks)
        bv23[n][ks] = *(const bf16x8*)&Bs[s][oB[n + 2] ^ (ks * 32)];
    #pragma unroll
    for (int ks = 0; ks < KS; ++ks)
      #pragma unroll
      for (int m = 0; m < MF; ++m)
        #pragma unroll
        for (int n = 0; n < 2; ++n)
          acc[m][n] = __builtin_amdgcn_mfma_f32_16x16x32_bf16(av[p][m][ks], bv01[n][ks], acc[m][n], 0, 0, 0);
    SB0();
    if (t + 2 < nt) { if constexpr (LPT == 4) VMW(4); else VMW(6); }
    else            { VMW(0); }
    BAR(); SB0();
    if (t + 1 < nt) {
      #pragma unroll
      for (int m = 0; m < MF; ++m)
        #pragma unroll
        for (int ks = 0; ks < KS; ++ks)
          av[p ^ 1][m][ks] = *(const bf16x8*)&As[s1][oA[m] ^ (ks * 32)];
      #pragma unroll
      for (int n = 0; n < 2; ++n)
        #pragma unroll
        for (int ks = 0; ks < KS; ++ks)
          bv01[n][ks] = *(const bf16x8*)&Bs[s1][oB[n] ^ (ks * 32)];
    }
    #pragma unroll
    for (int ks = 0; ks < KS; ++ks)
      #pragma unroll
      for (int m = 0; m < MF; ++m)
        #pragma unroll
        for (int n = 0; n < 2; ++n)
          acc[m][n + 2] = __builtin_amdgcn_mfma_f32_16x16x32_bf16(av[p][m][ks], bv23[n][ks], acc[m][n + 2], 0, 0, 0);
    SB0(); BAR(); SB0();
  }

  #pragma unroll
  for (int m = 0; m < MF; ++m) {
    const int row0 = by * BM + wm * (BM / 2) + m * 16 + lk * 4;
    #pragma unroll
    for (int n = 0; n < 4; ++n) {
      const int col = bx * 256 + wn * 64 + n * 16 + lrow;
      #pragma unroll
      for (int j = 0; j < 4; ++j) {
        const size_t idx = (size_t)(row0 + j) * N + col;
        if constexpr (OUT_BF16) ((ushort_t*)Cp)[idx] = f2bf(acc[m][n][j]);
        else                    ((float*)Cp)[idx] = acc[m][n][j];
      }
    }
  }
}

// =====================================================================
// gemmF: fused routing + output GEMM. out[8192x1024] = M @ W2t^T where
// M[t, n*128+r] = sum_p w[p,t,n]*h[p,t,r] is GENERATED ON-CHIP.
// Block: BM=128 tokens x BN=256 out-dims, BK=64, nt=32, 8 waves 2Mx4N.
// Pass 0: thread (token tid>>2, r-quarter tid&3) computes its own
// h[2][2half][16] (f32 accum -> packed bf16 regs) and, via quad-shfl
// reduce + per-lane softmax, w[2][16] (packed bf16 regs). The A-tile
// generator then reads ONLY its own registers: M elems for (token, its
// 16-col span) = w0*h0 + w1*h1, packed and ds_written to swizzled As.
// GEMM loop = gemmP's verified ledger with B-only vmcnt (LPT=4);
// genA ds_writes drained by LGKM0 before the P1 barrier.
// =====================================================================
__global__ __launch_bounds__(512, 2) void gemmF(const ushort_t* __restrict__ AH,
                                                const float* __restrict__ fp,
                                                const float* __restrict__ femb,
                                                const float* __restrict__ Wr,
                                                const ushort_t* __restrict__ Bt,
                                                float* __restrict__ out) {
  constexpr int nt = 32;
  __shared__ ushort_t As[3][128 * 64];
  __shared__ ushort_t Bs[3][256 * 64];
  __shared__ float Gs[16][16];
  __shared__ float WrBs[128 * 16];

  const int tid = threadIdx.x;
  const int nx = gridDim.x;
  const int orig = blockIdx.y * nx + blockIdx.x;
  const int q = (nx * gridDim.y) >> 3;
  const int swz = (orig & 7) * q + (orig >> 3);
  const int bx = swz % nx, by = swz / nx;

  const int lane = tid & 63, wv = tid >> 6;
  const int wm = wv >> 2, wn = wv & 3;
  const int lrow = lane & 15, lk = lane >> 4;

  // ---------- pass 0: G, WrB to LDS ----------
  if (tid < 256) {
    const int n = tid >> 4, j = tid & 15;
    float s = 0.f;
    #pragma unroll
    for (int ds = 0; ds < 64; ++ds) s += femb[n * 64 + ds] * Wr[ds * 16 + j];
    Gs[n][j] = s;
  }
  *(float4*)(WrBs + tid * 4) = *(const float4*)(Wr + 64 * 16 + tid * 4);

  // ---------- pass 0: per-thread h ----------
  const int trow = tid >> 2, rq = tid & 3;       // token-in-block, r-quarter
  const size_t tok = (size_t)by * 128 + trow;

  float fpv[2][16];
  #pragma unroll
  for (int p = 0; p < 2; ++p)
    #pragma unroll
    for (int n = 0; n < 16; ++n)
      fpv[p][n] = fp[(size_t)p * (T_TOK * 16) + tok * 16 + n];

  float hf[2][2][16];                            // [p][half][i], r = half*64+rq*16+i
  #pragma unroll
  for (int p = 0; p < 2; ++p)
    #pragma unroll
    for (int hh = 0; hh < 2; ++hh)
      #pragma unroll
      for (int i = 0; i < 16; ++i) hf[p][hh][i] = 0.f;

  const ushort_t* ahb = AH + tok * NRCOL + rq * 16;
  #pragma unroll
  for (int n = 0; n < 16; ++n)
    #pragma unroll
    for (int hh = 0; hh < 2; ++hh) {
      const u32x4 ua = *(const u32x4*)(ahb + n * 128 + hh * 64);
      const u32x4 ub = *(const u32x4*)(ahb + n * 128 + hh * 64 + 8);
      #pragma unroll
      for (int k = 0; k < 4; ++k) {
        const float e0 = bflo(ua[k]), e1 = bfhi(ua[k]);
        const float e2 = bflo(ub[k]), e3 = bfhi(ub[k]);
        #pragma unroll
        for (int p = 0; p < 2; ++p) {
          hf[p][hh][2 * k]     += fpv[p][n] * e0;
          hf[p][hh][2 * k + 1] += fpv[p][n] * e1;
          hf[p][hh][8 + 2 * k]     += fpv[p][n] * e2;
          hf[p][hh][8 + 2 * k + 1] += fpv[p][n] * e3;
        }
      }
    }
  __syncthreads();                               // Gs, WrBs ready

  // ---------- pass 0: logits, softmax -> packed w ----------
  float lw[2][16];
  #pragma unroll
  for (int p = 0; p < 2; ++p)
    #pragma unroll
    for (int j = 0; j < 16; ++j) lw[p][j] = 0.f;
  #pragma unroll
  for (int hh = 0; hh < 2; ++hh)
    #pragma unroll
    for (int i = 0; i < 16; ++i) {
      const float* wrow = WrBs + (hh * 64 + rq * 16 + i) * 16;
      #pragma unroll
      for (int j4 = 0; j4 < 4; ++j4) {
        const f32x4 wwv = *(const f32x4*)(wrow + j4 * 4);
        #pragma unroll
        for (int k = 0; k < 4; ++k) {
          lw[0][j4 * 4 + k] += hf[0][hh][i] * wwv[k];
          lw[1][j4 * 4 + k] += hf[1][hh][i] * wwv[k];
        }
      }
    }
  #pragma unroll
  for (int p = 0; p < 2; ++p)
    #pragma unroll
    for (int j = 0; j < 16; ++j) {
      lw[p][j] += __shfl_xor(lw[p][j], 1, 64);
      lw[p][j] += __shfl_xor(lw[p][j], 2, 64);
    }
  #pragma unroll
  for (int n = 0; n < 16; ++n)
    #pragma unroll
    for (int j4 = 0; j4 < 4; ++j4) {
      const f32x4 g = *(const f32x4*)&Gs[n][j4 * 4];
      #pragma unroll
      for (int k = 0; k < 4; ++k) {
        lw[0][j4 * 4 + k] += fpv[0][n] * g[k];
        lw[1][j4 * 4 + k] += fpv[1][n] * g[k];
      }
    }
  unsigned wpk[2][8];
  #pragma unroll
  for (int p = 0; p < 2; ++p) {
    float mx = lw[p][0];
    #pragma unroll
    for (int j = 1; j < 16; ++j) mx = fmaxf(mx, lw[p][j]);
    float e[16], sm = 0.f;
    #pragma unroll
    for (int j = 0; j < 16; ++j) { e[j] = __expf(lw[p][j] - mx); sm += e[j]; }
    const float inv = 1.f / sm;
    #pragma unroll
    for (int j2 = 0; j2 < 8; ++j2)
      wpk[p][j2] = (unsigned)f2bf(e[2 * j2] * inv) |
                   ((unsigned)f2bf(e[2 * j2 + 1] * inv) << 16);
  }
  unsigned hpk[2][2][8];
  #pragma unroll
  for (int p = 0; p < 2; ++p)
    #pragma unroll
    for (int hh = 0; hh < 2; ++hh)
      #pragma unroll
      for (int i2 = 0; i2 < 8; ++i2)
        hpk[p][hh][i2] = (unsigned)f2bf(hf[p][hh][2 * i2]) |
                         ((unsigned)f2bf(hf[p][hh][2 * i2 + 1]) << 16);

  // ---------- GEMM ----------
  const ushort_t* Bb = Bt + (size_t)bx * 256 * NRCOL;
  const int srow = tid >> 3;
  const int sch = (tid & 7) ^ (srow & 7);
  const ushort_t* pB[4];
  #pragma unroll
  for (int r = 0; r < 4; ++r) pB[r] = Bb + (size_t)(r * 64 + srow) * NRCOL + sch * 8;
  const int dL = tid * 8;

  auto stageB = [&](int s, int kt) {
    #pragma unroll
    for (int r = 0; r < 4; ++r) gload16(pB[r] + kt * 64, (void*)&Bs[s][r * 4096 + dL]);
  };
  auto genA = [&](int s, int kt) {
    const int n = kt >> 1, hh = kt & 1;
    const float w0 = (n & 1) ? bfhi(wpk[0][n >> 1]) : bflo(wpk[0][n >> 1]);
    const float w1 = (n & 1) ? bfhi(wpk[1][n >> 1]) : bflo(wpk[1][n >> 1]);
    u32x4 o0, o1;
    #pragma unroll
    for (int i2 = 0; i2 < 8; ++i2) {
      const unsigned h0 = hpk[0][hh][i2], h1 = hpk[1][hh][i2];
      const float a = w0 * bflo(h0) + w1 * bflo(h1);
      const float b = w0 * bfhi(h0) + w1 * bfhi(h1);
      const unsigned pk = (unsigned)f2bf(a) | ((unsigned)f2bf(b) << 16);
      if (i2 < 4) o0[i2] = pk; else o1[i2 - 4] = pk;
    }
    const int c0 = (rq * 2) ^ (trow & 7), c1 = (rq * 2 + 1) ^ (trow & 7);
    *(u32x4*)&As[s][trow * 64 + c0 * 8] = o0;
    *(u32x4*)&As[s][trow * 64 + c1 * 8] = o1;
  };

  int oA[4], oB[4];
  #pragma unroll
  for (int m = 0; m < 4; ++m) {
    const int r = wm * 64 + m * 16 + lrow;
    oA[m] = r * 64 + (lk ^ (r & 7)) * 8;
  }
  #pragma unroll
  for (int n = 0; n < 4; ++n) {
    const int r = wn * 64 + n * 16 + lrow;
    oB[n] = r * 64 + (lk ^ (r & 7)) * 8;
  }

  f32x4 acc[4][4];
  #pragma unroll
  for (int m = 0; m < 4; ++m)
    #pragma unroll
    for (int n = 0; n < 4; ++n)
      acc[m][n] = (f32x4){0.f, 0.f, 0.f, 0.f};

  stageB(0, 0); stageB(1, 1);
  genA(0, 0); genA(1, 1);
  LGKM0(); VMW(4);
  SB0(); BAR(); SB0();

  bf16x8 av[2][4][2], bv01[2][2], bv23[2][2];
  #pragma unroll
  for (int m = 0; m < 4; ++m)
    #pragma unroll
    for (int ks = 0; ks < 2; ++ks)
      av[0][m][ks] = *(const bf16x8*)&As[0][oA[m] ^ (ks * 32)];
  #pragma unroll
  for (int n = 0; n < 2; ++n)
    #pragma unroll
    for (int ks = 0; ks < 2; ++ks)
      bv01[n][ks] = *(const bf16x8*)&Bs[0][oB[n] ^ (ks * 32)];

  #pragma unroll
  for (int t = 0; t < nt; ++t) {
    const int s = t % 3, s1 = (t + 1) % 3, s2 = (t + 2) % 3;
    const int p = t & 1;
    // P1: stage B(t+2), gen A(t+2), read own bv23, MFMA H0
    if (t + 2 < nt) { stageB(s2, t + 2); genA(s2, t + 2); }
    #pragma unroll
    for (int n = 0; n < 2; ++n)
      #pragma unroll
      for (int ks = 0; ks < 2; ++ks)
        bv23[n][ks] = *(const bf16x8*)&Bs[s][oB[n + 2] ^ (ks * 32)];
    #pragma unroll
    for (int ks = 0; ks < 2; ++ks)
      #pragma unroll
      for (int m = 0; m < 4; ++m)
        #pragma unroll
        for (int n = 0; n < 2; ++n)
          acc[m][n] = __builtin_amdgcn_mfma_f32_16x16x32_bf16(av[p][m][ks], bv01[n][ks], acc[m][n], 0, 0, 0);
    SB0();
    LGKM0();                       // drain genA ds_writes before barrier
    if (t + 2 < nt) { VMW(4); } else { VMW(0); }
    SB0(); BAR(); SB0();
    // P2: read t+1's av + bv01; MFMA H1
    if (t + 1 < nt) {
      #pragma unroll
      for (int m = 0; m < 4; ++m)
        #pragma unroll
        for (int ks = 0; ks < 2; ++ks)
          av[p ^ 1][m][ks] = *(const bf16x8*)&As[s1][oA[m] ^ (ks * 32)];
      #pragma unroll
      for (int n = 0; n < 2; ++n)
        #pragma unroll
        for (int ks = 0; ks < 2; ++ks)
          bv01[n][ks] = *(const bf16x8*)&Bs[s1][oB[n] ^ (ks * 32)];
    }
    #pragma unroll
    for (int ks = 0; ks < 2; ++ks)
      #pragma unroll
      for (int m = 0; m < 4; ++m)
        #pragma unroll
        for (int n = 0; n < 2; ++n)
          acc[m][n + 2] = __builtin_amdgcn_mfma_f32_16x16x32_bf16(av[p][m][ks], bv23[n][ks], acc[m][n + 2], 0, 0, 0);
    SB0(); BAR(); SB0();
  }

  #pragma unroll
  for (int m = 0; m < 4; ++m) {
    const int row0 = by * 128 + wm * 64 + m * 16 + lk * 4;
    #pragma unroll
    for (int n = 0; n < 4; ++n) {
      const int col = bx * 256 + wn * 64 + n * 16 + lrow;
      #pragma unroll
      for (int j = 0; j < 4; ++j)
        out[(size_t)(row0 + j) * DIM + col] = acc[m][n][j];
    }
  }
  if (blockIdx.x == 0 && blockIdx.y == 0 && tid == 0)
    out[(size_t)T_TOK * DIM] = 0.f;            // restore_aux_loss
}

extern "C" void kernel_launch(void* const* d_in, const int* in_sizes, int n_in,
                              void* d_out, int out_size, void* d_ws, size_t ws_size,
                              hipStream_t stream) {
  const float* x    = (const float*)d_in[0];
  const float* fp   = (const float*)d_in[1];
  const float* fk   = (const float*)d_in[2];
  const float* rk   = (const float*)d_in[3];
  const float* femb = (const float*)d_in[4];
  const float* Wr   = (const float*)d_in[5];
  float* out = (float*)d_out;

  char* ws = (char*)d_ws;
  unsigned short* Xbf = (unsigned short*)ws;
  unsigned short* W1t = (unsigned short*)(ws + 16u * 1024 * 1024);
  unsigned short* W2t = (unsigned short*)(ws + 32u * 1024 * 1024);
  unsigned short* AH  = (unsigned short*)(ws + 36u * 1024 * 1024);

  cvt_f32_bf16<<<2048, 256, 0, stream>>>(x, Xbf, (T_TOK * DIM) / 4);
  tcvt<<<dim3(128 / 32, 1024 / 32, 16), 256, 0, stream>>>(fk, W1t, 1024, 128,
                                                          1024L * 128, 128L * 1024);
  tcvt<<<dim3(1024 / 32, 2048 / 32, 1), 256, 0, stream>>>(rk, W2t, 2048, 1024, 0, 0);
  // all_h = Xbf @ W1t^T -> AH bf16 [8192][2048]
  gemmP<256, 32, 1024, true><<<dim3(NRCOL / 256, T_TOK / 256), 512, 0, stream>>>(Xbf, W1t, AH, NRCOL);
  // fused routing + output GEMM -> d_out
  gemmF<<<dim3(DIM / 256, T_TOK / 128), 512, 0, stream>>>(AH, fp, femb, Wr, W2t, out);
}

// Round 10
// 126.385 us; speedup vs baseline: 3.8630x; 3.8630x over previous
//
#include <hip/hip_runtime.h>

typedef __attribute__((ext_vector_type(16))) float f32x16;
typedef __bf16 bf16x8 __attribute__((ext_vector_type(8)));
typedef unsigned short ushort_t;

#define T_TOK 8192   // B*S
#define DIM   1024   // D
#define NRCOL 2048   // N_FEAT * R

#define VMW(n)  asm volatile("s_waitcnt vmcnt(" #n ")" ::: "memory")
#define SB0()   __builtin_amdgcn_sched_barrier(0)
#define BAR()   __builtin_amdgcn_s_barrier()

static __device__ __forceinline__ unsigned short f2bf(float f) {
  unsigned int u = __builtin_bit_cast(unsigned int, f);
  u += 0x7fffu + ((u >> 16) & 1u);          // RNE
  return (unsigned short)(u >> 16);
}
static __device__ __forceinline__ float bfbits2f(unsigned int lo16) {
  return __builtin_bit_cast(float, lo16 << 16);
}
static __device__ __forceinline__ void gload16(const void* g, void* l) {
  __builtin_amdgcn_global_load_lds((const __attribute__((address_space(1))) void*)g,
                                   (__attribute__((address_space(3))) void*)l, 16, 0, 0);
}

// ---------------- f32 -> bf16 straight cast (x) ----------------
__global__ __launch_bounds__(256) void cvt_f32_bf16(const float* __restrict__ in,
                                                    unsigned short* __restrict__ out,
                                                    int n4) {
  int i = blockIdx.x * 256 + threadIdx.x;
  const int stride = gridDim.x * 256;
  const float4* in4 = (const float4*)in;
  uint2* o4 = (uint2*)out;
  for (; i < n4; i += stride) {
    float4 v = in4[i];
    uint2 o;
    o.x = (unsigned)f2bf(v.x) | ((unsigned)f2bf(v.y) << 16);
    o.y = (unsigned)f2bf(v.z) | ((unsigned)f2bf(v.w) << 16);
    o4[i] = o;
  }
}

// ---------------- tiled transpose + cast ----------------
__global__ __launch_bounds__(256) void tcvt(const float* __restrict__ src,
                                            unsigned short* __restrict__ dst,
                                            int rows, int cols,
                                            long sstride, long dstride) {
  src += (size_t)blockIdx.z * sstride;
  dst += (size_t)blockIdx.z * dstride;
  __shared__ float tile[32][33];
  const int tx = threadIdx.x & 31, ty = threadIdx.x >> 5;
  const int r0 = blockIdx.y * 32, c0 = blockIdx.x * 32;
  #pragma unroll
  for (int i = 0; i < 32; i += 8)
    tile[ty + i][tx] = src[(size_t)(r0 + ty + i) * cols + c0 + tx];
  __syncthreads();
  #pragma unroll
  for (int i = 0; i < 32; i += 8)
    dst[(size_t)(c0 + ty + i) * rows + r0 + tx] = f2bf(tile[tx][ty + i]);
}

// =====================================================================
// gemm32: C[M,N] = A[M,K]*Bt[N,K]^T with 32x32x16 MFMA.
// 128x256 tile, BK=64, 512 thr = 8 waves (2M x 4N, wave 64x64 = 2x2
// 32-blocks). R8's verified 3-slot / counted-vmcnt(6) / 1-barrier
// ledger. Frag layout (32x32x16): A lane l holds A[l&31][ks*16+hi*8+j]
// (hi=l>>5) -> chunk (ks*2+hi)^(r&7) -> elem off = base ^ ks*16.
// C/D: col=lane&31, row=(reg&3)+8*(reg>>2)+4*hi.
// =====================================================================
template<int K, bool OUT_BF16>
__global__ __launch_bounds__(512, 2) void gemm32(const ushort_t* __restrict__ A,
                                                 const ushort_t* __restrict__ Bt,
                                                 void* __restrict__ Cp, int N) {
  constexpr int nt = K / 64;
  __shared__ ushort_t As[3][128 * 64];
  __shared__ ushort_t Bs[3][256 * 64];

  const int tid = threadIdx.x;
  const int nx = gridDim.x;
  const int orig = blockIdx.y * nx + blockIdx.x;
  const int q = (nx * gridDim.y) >> 3;      // grids are multiples of 8
  const int swz = (orig & 7) * q + (orig >> 3);
  const int bx = swz % nx, by = swz / nx;

  const int lane = tid & 63, wv = tid >> 6;
  const int wm = wv >> 2, wn = wv & 3;      // 2M x 4N
  const int l31 = lane & 31, hi = lane >> 5;

  const ushort_t* Ab = A + (size_t)by * 128 * K;
  const ushort_t* Bb = Bt + (size_t)bx * 256 * K;

  // staging: AR=2 A rounds (64 rows each), BR=4 B rounds; LPT=6
  const int srow = tid >> 3;
  const int sch = (tid & 7) ^ (srow & 7);
  const ushort_t* pA[2];
  const ushort_t* pB[4];
  #pragma unroll
  for (int r = 0; r < 2; ++r) pA[r] = Ab + (size_t)(r * 64 + srow) * K + sch * 8;
  #pragma unroll
  for (int r = 0; r < 4; ++r) pB[r] = Bb + (size_t)(r * 64 + srow) * K + sch * 8;
  const int dL = tid * 8;

  auto stage = [&](int s, int adv) {
    #pragma unroll
    for (int r = 0; r < 2; ++r) gload16(pA[r] + adv, (void*)&As[s][r * 4096 + dL]);
    #pragma unroll
    for (int r = 0; r < 4; ++r) gload16(pB[r] + adv, (void*)&Bs[s][r * 4096 + dL]);
  };

  // frag base offsets (ks folds in as ^ (ks*16))
  int oA[2], oB[2];
  #pragma unroll
  for (int m = 0; m < 2; ++m) {
    const int r = wm * 64 + m * 32 + l31;
    oA[m] = r * 64 + (hi ^ (r & 7)) * 8;
  }
  #pragma unroll
  for (int n = 0; n < 2; ++n) {
    const int r = wn * 64 + n * 32 + l31;
    oB[n] = r * 64 + (hi ^ (r & 7)) * 8;
  }

  f32x16 acc[2][2];
  #pragma unroll
  for (int m = 0; m < 2; ++m)
    #pragma unroll
    for (int n = 0; n < 2; ++n)
      #pragma unroll
      for (int j = 0; j < 16; ++j) acc[m][n][j] = 0.f;

  // prologue: tiles 0,1 -> slots 0,1; retire tile0's 6, keep tile1's in flight
  stage(0, 0);
  stage(1, 64);
  VMW(6); SB0(); BAR(); SB0();

  #pragma unroll
  for (int t = 0; t < nt; ++t) {
    const int s = t % 3, s2 = (t + 2) % 3;
    bf16x8 av[2][4], bv[2][4];
    #pragma unroll
    for (int m = 0; m < 2; ++m)
      #pragma unroll
      for (int ks = 0; ks < 4; ++ks)
        av[m][ks] = *(const bf16x8*)&As[s][oA[m] ^ (ks * 16)];
    #pragma unroll
    for (int n = 0; n < 2; ++n)
      #pragma unroll
      for (int ks = 0; ks < 4; ++ks)
        bv[n][ks] = *(const bf16x8*)&Bs[s][oB[n] ^ (ks * 16)];
    if (t + 2 < nt) stage(s2, (t + 2) * 64);
    __builtin_amdgcn_s_setprio(1);
    #pragma unroll
    for (int ks = 0; ks < 4; ++ks)
      #pragma unroll
      for (int m = 0; m < 2; ++m)
        #pragma unroll
        for (int n = 0; n < 2; ++n)
          acc[m][n] = __builtin_amdgcn_mfma_f32_32x32x16_bf16(av[m][ks], bv[n][ks], acc[m][n], 0, 0, 0);
    __builtin_amdgcn_s_setprio(0);
    SB0();
    if (t + 2 < nt) { VMW(6); } else { VMW(0); }
    SB0(); BAR(); SB0();
  }

  // epilogue: C/D col=lane&31, row=(j&3)+8*(j>>2)+4*hi
  #pragma unroll
  for (int m = 0; m < 2; ++m) {
    const int row0 = by * 128 + wm * 64 + m * 32 + 4 * hi;
    #pragma unroll
    for (int n = 0; n < 2; ++n) {
      const int col = bx * 256 + wn * 64 + n * 32 + l31;
      #pragma unroll
      for (int j = 0; j < 16; ++j) {
        const int grow = row0 + (j & 3) + 8 * (j >> 2);
        const size_t idx = (size_t)grow * N + col;
        if constexpr (OUT_BF16) ((ushort_t*)Cp)[idx] = f2bf(acc[m][n][j]);
        else                    ((float*)Cp)[idx] = acc[m][n][j];
      }
    }
  }
}

// ---------------- middle: h_all, router softmax, M = sum_p w (x) h ----------------
__global__ __launch_bounds__(256) void middle_kernel(const unsigned short* __restrict__ AH,
                                                     const float* __restrict__ fp,
                                                     const float* __restrict__ femb,
                                                     const float* __restrict__ Wr,
                                                     unsigned short* __restrict__ Mout,
                                                     float* __restrict__ auxout) {
  __shared__ float G[16][16];
  __shared__ float hs[4][2][128];
  __shared__ float wsm[4][2][16];
  const int tid = threadIdx.x;
  {
    const int n = tid >> 4, j = tid & 15;
    float s = 0.f;
    #pragma unroll
    for (int ds = 0; ds < 64; ++ds) s += femb[n * 64 + ds] * Wr[ds * 16 + j];
    G[n][j] = s;
  }
  const int wv = tid >> 6, l = tid & 63;
  const int t = blockIdx.x * 4 + wv;

  float p0[16], p1[16];
  #pragma unroll
  for (int n = 0; n < 16; ++n) {
    p0[n] = fp[t * 16 + n];
    p1[n] = fp[T_TOK * 16 + t * 16 + n];
  }

  float h00 = 0.f, h01 = 0.f, h10 = 0.f, h11 = 0.f;
  const unsigned short* ahrow = AH + (size_t)t * NRCOL;
  #pragma unroll
  for (int n = 0; n < 16; ++n) {
    const unsigned int v = *(const unsigned int*)(ahrow + n * 128 + 2 * l);
    const float a0 = bfbits2f(v & 0xffffu);
    const float a1 = bfbits2f(v >> 16);
    h00 += a0 * p0[n]; h01 += a1 * p0[n];
    h10 += a0 * p1[n]; h11 += a1 * p1[n];
  }
  hs[wv][0][2 * l] = h00; hs[wv][0][2 * l + 1] = h01;
  hs[wv][1][2 * l] = h10; hs[wv][1][2 * l + 1] = h11;
  __syncthreads();

  if (l < 32) {
    const int p = l >> 4, j = l & 15;
    float s = 0.f;
    #pragma unroll
    for (int n = 0; n < 16; ++n) s += (p ? p1[n] : p0[n]) * G[n][j];
    const float* hp = hs[wv][p];
    const float* wr = Wr + 64 * 16 + j;
    float s0 = 0.f, s1 = 0.f, s2 = 0.f, s3 = 0.f;
    #pragma unroll
    for (int r = 0; r < 128; r += 4) {
      s0 += hp[r]     * wr[(r)     * 16];
      s1 += hp[r + 1] * wr[(r + 1) * 16];
      s2 += hp[r + 2] * wr[(r + 2) * 16];
      s3 += hp[r + 3] * wr[(r + 3) * 16];
    }
    s += (s0 + s1) + (s2 + s3);
    float mx = s;
    #pragma unroll
    for (int d = 1; d < 16; d <<= 1) mx = fmaxf(mx, __shfl_xor(mx, d, 64));
    const float e = __expf(s - mx);
    float sum = e;
    #pragma unroll
    for (int d = 1; d < 16; d <<= 1) sum += __shfl_xor(sum, d, 64);
    wsm[wv][p][j] = e / sum;
  }
  __syncthreads();

  unsigned short* mrow = Mout + (size_t)t * NRCOL;
  #pragma unroll
  for (int n = 0; n < 16; ++n) {
    const float w0 = wsm[wv][0][n], w1 = wsm[wv][1][n];
    const float m0 = w0 * h00 + w1 * h10;
    const float m1 = w0 * h01 + w1 * h11;
    const unsigned int pk = (unsigned)f2bf(m0) | ((unsigned)f2bf(m1) << 16);
    *(unsigned int*)(mrow + n * 128 + 2 * l) = pk;
  }
  if (blockIdx.x == 0 && tid == 0) auxout[0] = 0.f;
}

extern "C" void kernel_launch(void* const* d_in, const int* in_sizes, int n_in,
                              void* d_out, int out_size, void* d_ws, size_t ws_size,
                              hipStream_t stream) {
  const float* x    = (const float*)d_in[0];
  const float* fp   = (const float*)d_in[1];
  const float* fk   = (const float*)d_in[2];
  const float* rk   = (const float*)d_in[3];
  const float* femb = (const float*)d_in[4];
  const float* Wr   = (const float*)d_in[5];
  float* out = (float*)d_out;

  char* ws = (char*)d_ws;
  unsigned short* Xbf = (unsigned short*)ws;
  unsigned short* W1t = (unsigned short*)(ws + 16u * 1024 * 1024);
  unsigned short* Mb  = (unsigned short*)ws;
  unsigned short* W2t = (unsigned short*)(ws + 32u * 1024 * 1024);
  unsigned short* AH  = (unsigned short*)(ws + 36u * 1024 * 1024);

  cvt_f32_bf16<<<2048, 256, 0, stream>>>(x, Xbf, (T_TOK * DIM) / 4);
  tcvt<<<dim3(128 / 32, 1024 / 32, 16), 256, 0, stream>>>(fk, W1t, 1024, 128,
                                                          1024L * 128, 128L * 1024);
  tcvt<<<dim3(1024 / 32, 2048 / 32, 1), 256, 0, stream>>>(rk, W2t, 2048, 1024, 0, 0);
  // all_h = Xbf @ W1t^T -> AH bf16 [8192][2048]
  gemm32<1024, true><<<dim3(NRCOL / 256, T_TOK / 128), 512, 0, stream>>>(Xbf, W1t, AH, NRCOL);
  middle_kernel<<<T_TOK / 4, 256, 0, stream>>>(AH, fp, femb, Wr, Mb, out + 8388608);
  // output = Mb @ W2t^T -> f32 d_out [8192][1024]
  gemm32<2048, false><<<dim3(DIM / 256, T_TOK / 128), 512, 0, stream>>>(Mb, W2t, out, DIM);
}